// Round 1
// baseline (2792.488 us; speedup 1.0000x reference)
//
#include <hip/hip_runtime.h>

// Problem constants
constexpr int B_ = 8, E_ = 512, F_ = 1024, T_ = 2048, R_ = 10, L_ = 5;
constexpr int NTRI = 55; // 10*11/2

enum { EPI_STORE = 0, EPI_ERR = 1, EPI_AUPD = 2, EPI_AUPD0 = 3 };

// ---------------------------------------------------------------------------
// 10x10 SPD solve via unrolled Cholesky (packed lower-tri storage, all
// compile-time indices so everything stays in VGPRs).
// ---------------------------------------------------------------------------
__device__ __forceinline__ void solve10(float M[NTRI], const float rhs[R_],
                                        float lam, float x[R_]) {
#pragma unroll
  for (int j = 0; j < R_; j++) M[j * (j + 1) / 2 + j] += lam;
  // Cholesky factorization in place: M -> L (lower)
#pragma unroll
  for (int j = 0; j < R_; j++) {
    float s = M[j * (j + 1) / 2 + j];
#pragma unroll
    for (int k = 0; k < j; k++) {
      float l = M[j * (j + 1) / 2 + k];
      s -= l * l;
    }
    s = fmaxf(s, 1e-30f); // guard vs rounding on ill-conditioned M
    float d = sqrtf(s);
    float inv = 1.0f / d;
    M[j * (j + 1) / 2 + j] = d;
#pragma unroll
    for (int i = j + 1; i < R_; i++) {
      float s2 = M[i * (i + 1) / 2 + j];
#pragma unroll
      for (int k = 0; k < j; k++)
        s2 -= M[i * (i + 1) / 2 + k] * M[j * (j + 1) / 2 + k];
      M[i * (i + 1) / 2 + j] = s2 * inv;
    }
  }
  // forward: L y = rhs
  float y[R_];
#pragma unroll
  for (int i = 0; i < R_; i++) {
    float s = rhs[i];
#pragma unroll
    for (int k = 0; k < i; k++) s -= M[i * (i + 1) / 2 + k] * y[k];
    y[i] = s / M[i * (i + 1) / 2 + i];
  }
  // backward: L^T x = y
#pragma unroll
  for (int ii = R_ - 1; ii >= 0; ii--) {
    float s = y[ii];
#pragma unroll
    for (int k = ii + 1; k < R_; k++) s -= M[k * (k + 1) / 2 + ii] * x[k];
    x[ii] = s / M[ii * (ii + 1) / 2 + ii];
  }
}

__device__ __forceinline__ float sigmoidf_(float v) {
  return 1.0f / (1.0f + expf(-v));
}

// ---------------------------------------------------------------------------
// Tiled fp32 GEMM: C[M,N] = opA(A) @ B   (per-batch via blockIdx.z)
// TRANSA=0: A is [M,K] row-major (lda=K). TRANSA=1: physical A is [K,M]
// row-major (lda=M) and we compute A^T @ B. SQA squares A during staging.
// Epilogues fuse err / A-update.
// Tile 128x128, BK=8, 256 threads, 8x8 micro-tile.
// ---------------------------------------------------------------------------
template <int TRANSA, int SQA, int EPI>
__global__ __launch_bounds__(256) void gemm_k(
    const float* __restrict__ Ag, const float* __restrict__ Bg,
    float* __restrict__ Cg, const float* __restrict__ aux1,
    const float* __restrict__ aux2, const float* __restrict__ mu_log,
    const float* __restrict__ sk, int step, int M, int N, int K, long sA,
    long sB, long sC) {
  int b = blockIdx.z;
  const float* A = Ag + (long)b * sA;
  const float* Bm = Bg + (long)b * sB;
  float* C = Cg + (long)b * sC;
  const float* x1 = aux1 ? aux1 + (long)b * sC : nullptr;
  const float* x2 = aux2 ? aux2 + (long)b * sC : nullptr;

  __shared__ float As[8][132];
  __shared__ float Bs[8][132];

  int tid = threadIdx.x;
  int m0 = blockIdx.y * 128, n0 = blockIdx.x * 128;
  int tx = tid & 15, ty = tid >> 4;

  float acc[8][8];
#pragma unroll
  for (int i = 0; i < 8; i++)
#pragma unroll
    for (int j = 0; j < 8; j++) acc[i][j] = 0.0f;

  int bkk = tid >> 5, bn4 = (tid & 31) << 2;
  int amm = tid >> 1, ak4 = (tid & 1) << 2;

  for (int k0 = 0; k0 < K; k0 += 8) {
    float4 bv = *reinterpret_cast<const float4*>(
        &Bm[(long)(k0 + bkk) * N + n0 + bn4]);
    *reinterpret_cast<float4*>(&Bs[bkk][bn4]) = bv;
    if (TRANSA) {
      float4 av = *reinterpret_cast<const float4*>(
          &A[(long)(k0 + bkk) * M + m0 + bn4]);
      if (SQA) {
        av.x *= av.x; av.y *= av.y; av.z *= av.z; av.w *= av.w;
      }
      *reinterpret_cast<float4*>(&As[bkk][bn4]) = av;
    } else {
      float4 av = *reinterpret_cast<const float4*>(
          &A[(long)(m0 + amm) * K + k0 + ak4]);
      As[ak4 + 0][amm] = av.x;
      As[ak4 + 1][amm] = av.y;
      As[ak4 + 2][amm] = av.z;
      As[ak4 + 3][amm] = av.w;
    }
    __syncthreads();
#pragma unroll
    for (int kk = 0; kk < 8; kk++) {
      float a[8], bb[8];
      *reinterpret_cast<float4*>(&a[0]) =
          *reinterpret_cast<const float4*>(&As[kk][ty * 8]);
      *reinterpret_cast<float4*>(&a[4]) =
          *reinterpret_cast<const float4*>(&As[kk][ty * 8 + 4]);
      *reinterpret_cast<float4*>(&bb[0]) =
          *reinterpret_cast<const float4*>(&Bs[kk][tx * 8]);
      *reinterpret_cast<float4*>(&bb[4]) =
          *reinterpret_cast<const float4*>(&Bs[kk][tx * 8 + 4]);
#pragma unroll
      for (int i = 0; i < 8; i++)
#pragma unroll
        for (int j = 0; j < 8; j++)
          acc[i][j] = fmaf(a[i], bb[j], acc[i][j]);
    }
    __syncthreads();
  }

  float mu = 0.f, s2 = 0.f;
  if (EPI == EPI_AUPD || EPI == EPI_AUPD0) {
    mu = expf(mu_log[step]);
    s2 = sigmoidf_(sk[step * 3 + 2]);
  }
#pragma unroll
  for (int i = 0; i < 8; i++) {
    int m = m0 + ty * 8 + i;
    long row = (long)m * N + n0 + tx * 8;
#pragma unroll
    for (int j4 = 0; j4 < 8; j4 += 4) {
      if (EPI == EPI_STORE) {
        float4 v;
        v.x = acc[i][j4 + 0]; v.y = acc[i][j4 + 1];
        v.z = acc[i][j4 + 2]; v.w = acc[i][j4 + 3];
        *reinterpret_cast<float4*>(&C[row + j4]) = v;
      } else if (EPI == EPI_ERR) {
        float4 om = *reinterpret_cast<const float4*>(&x1[row + j4]);
        float4 yv = *reinterpret_cast<const float4*>(&x2[row + j4]);
        float4 v;
        v.x = om.x * (yv.x - acc[i][j4 + 0]);
        v.y = om.y * (yv.y - acc[i][j4 + 1]);
        v.z = om.z * (yv.z - acc[i][j4 + 2]);
        v.w = om.w * (yv.w - acc[i][j4 + 3]);
        *reinterpret_cast<float4*>(&C[row + j4]) = v;
      } else {
        float4 as4 = *reinterpret_cast<const float4*>(&x1[row + j4]);
        float4 aold;
        if (EPI == EPI_AUPD)
          aold = *reinterpret_cast<const float4*>(&C[row + j4]);
        else {
          aold.x = 0.f; aold.y = 0.f; aold.z = 0.f; aold.w = 0.f;
        }
        float av[4], sv[4], ov[4];
        av[0] = as4.x; av[1] = as4.y; av[2] = as4.z; av[3] = as4.w;
        ov[0] = aold.x; ov[1] = aold.y; ov[2] = aold.z; ov[3] = aold.w;
#pragma unroll
        for (int c = 0; c < 4; c++) {
          float bat = fmaf(av[c], ov[c], acc[i][j4 + c]);
          float mag = fmaxf(fabsf(bat) - mu, 0.0f);
          float sft = bat > 0.f ? mag : (bat < 0.f ? -mag : 0.f);
          float ahat = (av[c] == 0.f) ? 0.f : sft / av[c];
          sv[c] = ov[c] + s2 * (ahat - ov[c]);
        }
        float4 v;
        v.x = sv[0]; v.y = sv[1]; v.z = sv[2]; v.w = sv[3];
        *reinterpret_cast<float4*>(&C[row + j4]) = v;
      }
    }
  }
}

// ---------------------------------------------------------------------------
// err = Omega * Y   (step 0, A == 0)
// ---------------------------------------------------------------------------
__global__ __launch_bounds__(256) void errinit_k(float* __restrict__ err,
                                                 const float* __restrict__ Om,
                                                 const float* __restrict__ Y) {
  long i = ((long)blockIdx.x * 256 + threadIdx.x) * 4;
  float4 o = *reinterpret_cast<const float4*>(&Om[i]);
  float4 y = *reinterpret_cast<const float4*>(&Y[i]);
  float4 v;
  v.x = o.x * y.x; v.y = o.y * y.y; v.z = o.z * y.z; v.w = o.w * y.w;
  *reinterpret_cast<float4*>(&err[i]) = v;
}

// ---------------------------------------------------------------------------
// P update: one wave per (b,e). Lanes stride t; butterfly-reduce the 55+10
// accumulators; Cholesky solve; blend; lane0 writes.
// ---------------------------------------------------------------------------
__global__ __launch_bounds__(256) void p_update_k(
    const float* __restrict__ Omega, const float* __restrict__ err,
    const float* __restrict__ Qin, const float* __restrict__ Pin,
    float* __restrict__ Pout, const float* __restrict__ lam_log,
    const float* __restrict__ sk, int step) {
  int wid = (blockIdx.x << 2) + (threadIdx.x >> 6); // = b*E_ + e
  int lane = threadIdx.x & 63;
  int b = wid >> 9;
  const float* om = Omega + (long)wid * T_;
  const float* er = err + (long)wid * T_;
  const float* Qb = Qin + (long)b * T_ * R_;

  float Ms[NTRI], rhs[R_], x[R_];
#pragma unroll
  for (int i = 0; i < NTRI; i++) Ms[i] = 0.f;
#pragma unroll
  for (int i = 0; i < R_; i++) rhs[i] = 0.f;

  for (int t = lane; t < T_; t += 64) {
    float w = om[t], ev = er[t];
    float q[R_];
#pragma unroll
    for (int r = 0; r < R_; r += 2) {
      float2 v = *reinterpret_cast<const float2*>(&Qb[(long)t * R_ + r]);
      q[r] = v.x; q[r + 1] = v.y;
    }
    float wq[R_];
#pragma unroll
    for (int r = 0; r < R_; r++) {
      wq[r] = w * q[r];
      rhs[r] = fmaf(ev, q[r], rhs[r]);
    }
    int idx = 0;
#pragma unroll
    for (int r = 0; r < R_; r++)
#pragma unroll
      for (int s = 0; s <= r; s++) {
        Ms[idx] = fmaf(wq[r], q[s], Ms[idx]);
        idx++;
      }
  }
  // butterfly reduce across 64 lanes (all lanes end with the full sums)
#pragma unroll
  for (int off = 32; off > 0; off >>= 1) {
#pragma unroll
    for (int i = 0; i < NTRI; i++) Ms[i] += __shfl_xor(Ms[i], off, 64);
#pragma unroll
    for (int i = 0; i < R_; i++) rhs[i] += __shfl_xor(rhs[i], off, 64);
  }
  float lam = expf(lam_log[step]);
  solve10(Ms, rhs, lam, x);
  if (lane == 0) {
    float s0 = sigmoidf_(sk[step * 3 + 0]);
#pragma unroll
    for (int r = 0; r < R_; r++) {
      float pold = Pin[(long)wid * R_ + r];
      Pout[(long)wid * R_ + r] = pold + s0 * (x[r] - pold);
    }
  }
}

// ---------------------------------------------------------------------------
// Q update: block = 4 waves handles (b, 64 t's). Lane = t (coalesced Omega/err
// reads), each wave sums a quarter of E, LDS-reduce, per-lane solve.
// ---------------------------------------------------------------------------
__global__ __launch_bounds__(256) void q_update_k(
    const float* __restrict__ Omega, const float* __restrict__ err,
    const float* __restrict__ Pn, const float* __restrict__ Qin,
    float* __restrict__ Qout, const float* __restrict__ lam_log,
    const float* __restrict__ sk, int step) {
  __shared__ float red[NTRI + R_][64];
  int b = blockIdx.x >> 5;  // T_/64 = 32 tiles
  int tt = blockIdx.x & 31;
  int w = threadIdx.x >> 6, lane = threadIdx.x & 63;
  int t = (tt << 6) + lane;
  const float* om = Omega + (long)b * E_ * T_ + t;
  const float* er = err + (long)b * E_ * T_ + t;
  const float* Pb = Pn + (long)b * E_ * R_;

  float Ms[NTRI], rhs[R_];
#pragma unroll
  for (int i = 0; i < NTRI; i++) Ms[i] = 0.f;
#pragma unroll
  for (int i = 0; i < R_; i++) rhs[i] = 0.f;

  for (int e = w * (E_ / 4); e < (w + 1) * (E_ / 4); e++) {
    float p[R_];
#pragma unroll
    for (int r = 0; r < R_; r += 2) {
      float2 v = *reinterpret_cast<const float2*>(&Pb[(long)e * R_ + r]);
      p[r] = v.x; p[r + 1] = v.y;
    }
    float wv = om[(long)e * T_];
    float ev = er[(long)e * T_];
    float wp[R_];
#pragma unroll
    for (int r = 0; r < R_; r++) {
      wp[r] = wv * p[r];
      rhs[r] = fmaf(ev, p[r], rhs[r]);
    }
    int idx = 0;
#pragma unroll
    for (int r = 0; r < R_; r++)
#pragma unroll
      for (int s = 0; s <= r; s++) {
        Ms[idx] = fmaf(wp[r], p[s], Ms[idx]);
        idx++;
      }
  }
  // cross-wave reduction (serialized adds, 4 barriers)
  for (int ww = 0; ww < 4; ww++) {
    if (w == ww) {
      if (ww == 0) {
#pragma unroll
        for (int i = 0; i < NTRI; i++) red[i][lane] = Ms[i];
#pragma unroll
        for (int i = 0; i < R_; i++) red[NTRI + i][lane] = rhs[i];
      } else {
#pragma unroll
        for (int i = 0; i < NTRI; i++) red[i][lane] += Ms[i];
#pragma unroll
        for (int i = 0; i < R_; i++) red[NTRI + i][lane] += rhs[i];
      }
    }
    __syncthreads();
  }
  if (w == 0) {
#pragma unroll
    for (int i = 0; i < NTRI; i++) Ms[i] = red[i][lane];
#pragma unroll
    for (int i = 0; i < R_; i++) rhs[i] = red[NTRI + i][lane];
    float lam = expf(lam_log[step]);
    float x[R_];
    solve10(Ms, rhs, lam, x);
    float s1 = sigmoidf_(sk[step * 3 + 1]);
    long qi = ((long)b * T_ + t) * R_;
#pragma unroll
    for (int r = 0; r < R_; r++) {
      float qold = Qin[qi + r];
      Qout[qi + r] = qold + s1 * (x[r] - qold);
    }
  }
}

// ---------------------------------------------------------------------------
// datafit (in place over err): err -= Omega * (P_new[b,e,:] . Q_new[b,t,:])
// One block per (b, e, 256-t chunk).
// ---------------------------------------------------------------------------
__global__ __launch_bounds__(256) void datafit_k(
    float* __restrict__ errio, const float* __restrict__ Omega,
    const float* __restrict__ Pn, const float* __restrict__ Qn) {
  int blk = blockIdx.x;
  int tch = blk & 7;           // T_/256 = 8
  int e = (blk >> 3) & 511;
  int b = blk >> 12;
  int t = tch * 256 + threadIdx.x;
  long base = ((long)b * E_ + e) * T_ + t;
  float p[R_];
#pragma unroll
  for (int r = 0; r < R_; r++) p[r] = Pn[((long)b * E_ + e) * R_ + r];
  float q[R_];
#pragma unroll
  for (int r = 0; r < R_; r += 2) {
    float2 v = *reinterpret_cast<const float2*>(&Qn[((long)b * T_ + t) * R_ + r]);
    q[r] = v.x; q[r + 1] = v.y;
  }
  float dot = 0.f;
#pragma unroll
  for (int r = 0; r < R_; r++) dot = fmaf(p[r], q[r], dot);
  errio[base] -= Omega[base] * dot;
}

// ---------------------------------------------------------------------------
extern "C" void kernel_launch(void* const* d_in, const int* in_sizes, int n_in,
                              void* d_out, int out_size, void* d_ws,
                              size_t ws_size, hipStream_t stream) {
  const float* Y = (const float*)d_in[0];
  const float* Rm = (const float*)d_in[1];
  const float* Om = (const float*)d_in[2];
  const float* P0 = (const float*)d_in[3];
  const float* Q0 = (const float*)d_in[4];
  const float* lam_log = (const float*)d_in[6];
  const float* mu_log = (const float*)d_in[7];
  const float* sk = (const float*)d_in[8];

  float* ws = (float*)d_ws;
  float* err = ws;                                   // B*E*T = 8,388,608
  float* Ascale = ws + (long)B_ * E_ * T_;           // B*F*T = 16,777,216
  float* Pa = Ascale + (long)B_ * F_ * T_;
  float* Pb = Pa + B_ * E_ * R_;
  float* Qa = Pb + B_ * E_ * R_;
  float* Qb = Qa + B_ * T_ * R_;

  float* outP = (float*)d_out;
  float* outQ = outP + B_ * E_ * R_;
  float* outA = outP + B_ * E_ * R_ + B_ * T_ * R_;

  const float* Pr[L_] = {P0, Pa, Pb, Pa, Pb};
  float* Pw[L_] = {Pa, Pb, Pa, Pb, outP};
  const float* Qr[L_] = {Q0, Qa, Qb, Qa, Qb};
  float* Qw[L_] = {Qa, Qb, Qa, Qb, outQ};

  const long sR = (long)E_ * F_;   // R batch stride
  const long sET = (long)E_ * T_;  // [E,T] batch stride
  const long sFT = (long)F_ * T_;  // [F,T] batch stride

  // A_scale = (R*R)^T @ Omega  (loop-invariant)
  gemm_k<1, 1, EPI_STORE><<<dim3(T_ / 128, F_ / 128, B_), 256, 0, stream>>>(
      Rm, Om, Ascale, nullptr, nullptr, nullptr, nullptr, 0, F_, T_, E_, sR,
      sET, sFT);

  for (int s = 0; s < L_; s++) {
    if (s == 0) {
      errinit_k<<<(B_ * E_ * T_) / 1024, 256, 0, stream>>>(err, Om, Y);
    } else {
      // err = Omega * (Y - R @ A)
      gemm_k<0, 0, EPI_ERR><<<dim3(T_ / 128, E_ / 128, B_), 256, 0, stream>>>(
          Rm, outA, err, Om, Y, nullptr, nullptr, s, E_, T_, F_, sR, sFT, sET);
    }
    p_update_k<<<(B_ * E_) / 4, 256, 0, stream>>>(Om, err, Qr[s], Pr[s], Pw[s],
                                                  lam_log, sk, s);
    q_update_k<<<B_ * (T_ / 64), 256, 0, stream>>>(Om, err, Pw[s], Qr[s],
                                                   Qw[s], lam_log, sk, s);
    datafit_k<<<B_ * E_ * (T_ / 256), 256, 0, stream>>>(err, Om, Pw[s], Qw[s]);
    // A update: BAt = R^T @ datafit, fused soft-threshold epilogue (in-place A)
    if (s == 0)
      gemm_k<1, 0, EPI_AUPD0><<<dim3(T_ / 128, F_ / 128, B_), 256, 0,
                                stream>>>(Rm, err, outA, Ascale, nullptr,
                                          mu_log, sk, s, F_, T_, E_, sR, sET,
                                          sFT);
    else
      gemm_k<1, 0, EPI_AUPD><<<dim3(T_ / 128, F_ / 128, B_), 256, 0, stream>>>(
          Rm, err, outA, Ascale, nullptr, mu_log, sk, s, F_, T_, E_, sR, sET,
          sFT);
  }
}

// Round 2
// 2422.713 us; speedup vs baseline: 1.1526x; 1.1526x over previous
//
#include <hip/hip_runtime.h>

constexpr int B_ = 8, E_ = 512, F_ = 1024, T_ = 2048, R_ = 10, L_ = 5;
constexpr int NTRI = 55;
constexpr int BM_ = 128, BN_ = 256, BK_ = 32;

enum { EPI_STORE = 0, EPI_ERR = 1, EPI_AUPD = 2, EPI_AUPD0 = 3 };

typedef __attribute__((ext_vector_type(4))) float f32x4;
typedef __attribute__((ext_vector_type(8))) short short8v;
union U8 { unsigned u[4]; short8v s; };

// ---------------------------------------------------------------------------
// fp32 -> (hi,lo) bf16 split, packed in one u32 (hi in low 16, lo in high 16)
// ---------------------------------------------------------------------------
__device__ __forceinline__ unsigned bf16r(float v) {
  unsigned u = __float_as_uint(v);
  return (u + 0x7fffu + ((u >> 16) & 1u)) >> 16;
}
__device__ __forceinline__ unsigned pack1(float v) {
  unsigned h = bf16r(v);
  float lo = v - __uint_as_float(h << 16);
  return h | (bf16r(lo) << 16);
}
__device__ __forceinline__ uint4 pack4(float4 v) {
  uint4 r;
  r.x = pack1(v.x); r.y = pack1(v.y); r.z = pack1(v.z); r.w = pack1(v.w);
  return r;
}
__device__ __forceinline__ void unpack8(uint4 w0, uint4 w1, U8& hi, U8& lo) {
  hi.u[0] = __builtin_amdgcn_perm(w0.y, w0.x, 0x05040100u);
  lo.u[0] = __builtin_amdgcn_perm(w0.y, w0.x, 0x07060302u);
  hi.u[1] = __builtin_amdgcn_perm(w0.w, w0.z, 0x05040100u);
  lo.u[1] = __builtin_amdgcn_perm(w0.w, w0.z, 0x07060302u);
  hi.u[2] = __builtin_amdgcn_perm(w1.y, w1.x, 0x05040100u);
  lo.u[2] = __builtin_amdgcn_perm(w1.y, w1.x, 0x07060302u);
  hi.u[3] = __builtin_amdgcn_perm(w1.w, w1.z, 0x05040100u);
  lo.u[3] = __builtin_amdgcn_perm(w1.w, w1.z, 0x07060302u);
}

__device__ __forceinline__ float sigmoidf_(float v) {
  return 1.0f / (1.0f + expf(-v));
}

// ---------------------------------------------------------------------------
// 10x10 SPD solve, unrolled Cholesky, packed lower-tri (compile-time indices)
// ---------------------------------------------------------------------------
__device__ __forceinline__ void solve10(float M[NTRI], const float rhs[R_],
                                        float lam, float x[R_]) {
#pragma unroll
  for (int j = 0; j < R_; j++) M[j * (j + 1) / 2 + j] += lam;
#pragma unroll
  for (int j = 0; j < R_; j++) {
    float s = M[j * (j + 1) / 2 + j];
#pragma unroll
    for (int k = 0; k < j; k++) {
      float l = M[j * (j + 1) / 2 + k];
      s -= l * l;
    }
    s = fmaxf(s, 1e-30f);
    float d = sqrtf(s);
    float inv = 1.0f / d;
    M[j * (j + 1) / 2 + j] = d;
#pragma unroll
    for (int i = j + 1; i < R_; i++) {
      float s2 = M[i * (i + 1) / 2 + j];
#pragma unroll
      for (int k = 0; k < j; k++)
        s2 -= M[i * (i + 1) / 2 + k] * M[j * (j + 1) / 2 + k];
      M[i * (i + 1) / 2 + j] = s2 * inv;
    }
  }
  float y[R_];
#pragma unroll
  for (int i = 0; i < R_; i++) {
    float s = rhs[i];
#pragma unroll
    for (int k = 0; k < i; k++) s -= M[i * (i + 1) / 2 + k] * y[k];
    y[i] = s / M[i * (i + 1) / 2 + i];
  }
#pragma unroll
  for (int ii = R_ - 1; ii >= 0; ii--) {
    float s = y[ii];
#pragma unroll
    for (int k = ii + 1; k < R_; k++) s -= M[k * (k + 1) / 2 + ii] * x[k];
    x[ii] = s / M[ii * (ii + 1) / 2 + ii];
  }
}

// ---------------------------------------------------------------------------
// Tiled transpose: in [Rw,Cl] -> out [Cl,Rw], per-batch (blockIdx.z).
// MODE 1: out = transpose(in0*in1)
// ---------------------------------------------------------------------------
template <int MODE>
__global__ __launch_bounds__(256) void trans_k(const float* __restrict__ in0,
                                               const float* __restrict__ in1,
                                               float* __restrict__ out, int Rw,
                                               int Cl) {
  __shared__ float tile[32][36];
  long ib = (long)blockIdx.z * Rw * Cl;
  int r0 = blockIdx.y * 32, c0 = blockIdx.x * 32;
  int tid = threadIdx.x;
  int c4 = (tid & 7) << 2, r = tid >> 3;
  float4 v = *(const float4*)(in0 + ib + (long)(r0 + r) * Cl + c0 + c4);
  if (MODE == 1) {
    float4 w = *(const float4*)(in1 + ib + (long)(r0 + r) * Cl + c0 + c4);
    v.x *= w.x; v.y *= w.y; v.z *= w.z; v.w *= w.w;
  }
  *(float4*)&tile[r][c4] = v;
  __syncthreads();
  int co = tid >> 3, ro4 = (tid & 7) << 2;
  float4 o;
  o.x = tile[ro4 + 0][co];
  o.y = tile[ro4 + 1][co];
  o.z = tile[ro4 + 2][co];
  o.w = tile[ro4 + 3][co];
  *(float4*)(out + ib + (long)(c0 + co) * Rw + r0 + ro4) = o;
}

// ---------------------------------------------------------------------------
// Split-bf16 MFMA GEMM: C[M,N] = Aop[M,K] @ Bop[N,K]^T, all K-contiguous.
// 256 threads = 4 waves; block tile 128x256, wave tile 64x128, BK=32.
// LDS holds hi|lo-packed u32, XOR-swizzled at 16B granularity.
// ---------------------------------------------------------------------------
template <int EPI, int SQB>
__global__ __launch_bounds__(256, 2) void gemm_split(
    const float* __restrict__ Ag, const float* __restrict__ Bg,
    float* __restrict__ Cg, const float* __restrict__ aux1,
    const float* __restrict__ aux2, const float* __restrict__ mu_log,
    const float* __restrict__ sk, int step, int M, int N, int K, long sA,
    long sB, long sC) {
  __shared__ unsigned As[BM_ * BK_];
  __shared__ unsigned Bs[BN_ * BK_];
  int b = blockIdx.z;
  const float* A = Ag + (long)b * sA;
  const float* Bop = Bg + (long)b * sB;
  float* C = Cg + (long)b * sC;
  const float* x1 = aux1 ? aux1 + (long)b * sC : nullptr;
  const float* x2 = aux2 ? aux2 + (long)b * sC : nullptr;

  int tid = threadIdx.x;
  int m0 = blockIdx.y * BM_, n0 = blockIdx.x * BN_;
  int g = tid & 7, rb = tid >> 3;
  int g4 = g << 2;
  int l = tid & 63, lr = l & 15, lh = l >> 4;
  int wv = tid >> 6, wr = wv >> 1, wc = wv & 1;

  f32x4 acc[4][8];
#pragma unroll
  for (int i = 0; i < 4; i++)
#pragma unroll
    for (int j = 0; j < 8; j++) acc[i][j] = {0.f, 0.f, 0.f, 0.f};

  float4 va[4], vb[8];
#pragma unroll
  for (int p = 0; p < 4; p++)
    va[p] = *(const float4*)&A[(long)(m0 + rb + 32 * p) * K + g4];
#pragma unroll
  for (int p = 0; p < 8; p++)
    vb[p] = *(const float4*)&Bop[(long)(n0 + rb + 32 * p) * K + g4];

  for (int kt = 0; kt < K; kt += BK_) {
    uint4 pa[4], pb[8];
#pragma unroll
    for (int p = 0; p < 4; p++) pa[p] = pack4(va[p]);
#pragma unroll
    for (int p = 0; p < 8; p++) {
      float4 v = vb[p];
      if (SQB) { v.x *= v.x; v.y *= v.y; v.z *= v.z; v.w *= v.w; }
      pb[p] = pack4(v);
    }
    __syncthreads();
#pragma unroll
    for (int p = 0; p < 4; p++) {
      int row = rb + 32 * p;
      *(uint4*)&As[row * BK_ + ((g ^ (row & 7)) << 2)] = pa[p];
    }
#pragma unroll
    for (int p = 0; p < 8; p++) {
      int row = rb + 32 * p;
      *(uint4*)&Bs[row * BK_ + ((g ^ (row & 7)) << 2)] = pb[p];
    }
    __syncthreads();
    if (kt + BK_ < K) {  // prefetch next tile (overlaps compute)
#pragma unroll
      for (int p = 0; p < 4; p++)
        va[p] = *(const float4*)&A[(long)(m0 + rb + 32 * p) * K + kt + BK_ + g4];
#pragma unroll
      for (int p = 0; p < 8; p++)
        vb[p] = *(const float4*)&Bop[(long)(n0 + rb + 32 * p) * K + kt + BK_ + g4];
    }
    // compute
    U8 aH[4], aL[4];
#pragma unroll
    for (int mf = 0; mf < 4; mf++) {
      int m = wr * 64 + mf * 16 + lr;
      int s7 = m & 7, g0 = 2 * lh;
      uint4 w0 = *(const uint4*)&As[m * BK_ + ((g0 ^ s7) << 2)];
      uint4 w1 = *(const uint4*)&As[m * BK_ + (((g0 + 1) ^ s7) << 2)];
      unpack8(w0, w1, aH[mf], aL[mf]);
    }
#pragma unroll
    for (int nf = 0; nf < 8; nf++) {
      int n = wc * 128 + nf * 16 + lr;
      int s7 = n & 7, g0 = 2 * lh;
      uint4 w0 = *(const uint4*)&Bs[n * BK_ + ((g0 ^ s7) << 2)];
      uint4 w1 = *(const uint4*)&Bs[n * BK_ + (((g0 + 1) ^ s7) << 2)];
      U8 bH, bL;
      unpack8(w0, w1, bH, bL);
#pragma unroll
      for (int mf = 0; mf < 4; mf++) {
        acc[mf][nf] = __builtin_amdgcn_mfma_f32_16x16x32_bf16(
            aH[mf].s, bH.s, acc[mf][nf], 0, 0, 0);
        acc[mf][nf] = __builtin_amdgcn_mfma_f32_16x16x32_bf16(
            aL[mf].s, bH.s, acc[mf][nf], 0, 0, 0);
        acc[mf][nf] = __builtin_amdgcn_mfma_f32_16x16x32_bf16(
            aH[mf].s, bL.s, acc[mf][nf], 0, 0, 0);
      }
    }
  }

  float mu = 0.f, s2 = 0.f;
  if (EPI == EPI_AUPD || EPI == EPI_AUPD0) {
    mu = expf(mu_log[step]);
    s2 = sigmoidf_(sk[step * 3 + 2]);
  }
#pragma unroll
  for (int mf = 0; mf < 4; mf++) {
#pragma unroll
    for (int nf = 0; nf < 8; nf++) {
#pragma unroll
      for (int r = 0; r < 4; r++) {
        int m = m0 + wr * 64 + mf * 16 + lh * 4 + r;
        int n = n0 + wc * 128 + nf * 16 + lr;
        long idx = (long)m * N + n;
        float c = acc[mf][nf][r];
        if (EPI == EPI_STORE) {
          C[idx] = c;
        } else if (EPI == EPI_ERR) {
          C[idx] = x1[idx] - x2[idx] * c;  // YOm - OmT*(R@A)^T
        } else {
          float asv = x1[idx];
          float aold = (EPI == EPI_AUPD) ? C[idx] : 0.f;
          float bat = fmaf(asv, aold, c);
          float mag = fmaxf(fabsf(bat) - mu, 0.f);
          float sft = copysignf(mag, bat);
          float ahat = (asv == 0.f) ? 0.f : sft / asv;
          C[idx] = aold + s2 * (ahat - aold);
        }
      }
    }
  }
}

// ---------------------------------------------------------------------------
// P stage 1: lane = e (coalesced errT/OmT), partial sums over a t-chunk.
// scr layout: [b][tc(16)][i(65)][e(512)]
// ---------------------------------------------------------------------------
__global__ __launch_bounds__(256) void p_stage1(const float* __restrict__ errT,
                                                const float* __restrict__ OmT,
                                                const float* __restrict__ Q,
                                                float* __restrict__ scr) {
  int tc = blockIdx.x, eb = blockIdx.y, b = blockIdx.z;
  int e = eb * 256 + threadIdx.x;
  float Ms[NTRI], rhs[R_];
#pragma unroll
  for (int i = 0; i < NTRI; i++) Ms[i] = 0.f;
#pragma unroll
  for (int i = 0; i < R_; i++) rhs[i] = 0.f;
  long base = (long)b * T_ * E_ + e;
  for (int t = tc * 128; t < tc * 128 + 128; ++t) {
    const float* qr = Q + ((long)b * T_ + t) * R_;
    float q[R_];
#pragma unroll
    for (int r = 0; r < R_; r++) q[r] = qr[r];
    float w = OmT[base + (long)t * E_];
    float ev = errT[base + (long)t * E_];
    float wq[R_];
#pragma unroll
    for (int r = 0; r < R_; r++) {
      wq[r] = w * q[r];
      rhs[r] = fmaf(ev, q[r], rhs[r]);
    }
    int idx = 0;
#pragma unroll
    for (int r = 0; r < R_; r++)
#pragma unroll
      for (int s = 0; s <= r; s++) {
        Ms[idx] = fmaf(wq[r], q[s], Ms[idx]);
        idx++;
      }
  }
  long so = ((long)b * 16 + tc) * 65 * E_ + e;
#pragma unroll
  for (int i = 0; i < NTRI; i++) scr[so + (long)i * E_] = Ms[i];
#pragma unroll
  for (int i = 0; i < R_; i++) scr[so + (long)(NTRI + i) * E_] = rhs[i];
}

__global__ __launch_bounds__(256) void p_stage2(
    const float* __restrict__ scr, const float* __restrict__ Pin,
    float* __restrict__ Pout, const float* __restrict__ lam_log,
    const float* __restrict__ sk, int step) {
  int idx = blockIdx.x * 256 + threadIdx.x;  // b*E + e
  int b = idx >> 9, e = idx & 511;
  float Ms[NTRI], rhs[R_], x[R_];
#pragma unroll
  for (int i = 0; i < NTRI; i++) Ms[i] = 0.f;
#pragma unroll
  for (int i = 0; i < R_; i++) rhs[i] = 0.f;
  for (int tc = 0; tc < 16; ++tc) {
    long so = ((long)b * 16 + tc) * 65 * E_ + e;
#pragma unroll
    for (int i = 0; i < NTRI; i++) Ms[i] += scr[so + (long)i * E_];
#pragma unroll
    for (int i = 0; i < R_; i++) rhs[i] += scr[so + (long)(NTRI + i) * E_];
  }
  float lam = expf(lam_log[step]);
  solve10(Ms, rhs, lam, x);
  float s0 = sigmoidf_(sk[step * 3 + 0]);
#pragma unroll
  for (int r = 0; r < R_; r++) {
    float pold = Pin[(long)idx * R_ + r];
    Pout[(long)idx * R_ + r] = pold + s0 * (x[r] - pold);
  }
}

// ---------------------------------------------------------------------------
// Q stage 1: lane = t, loop e-chunk (strided reads, L1-amortized).
// scr layout: [b][ec(4)][i(65)][t(2048)]
// ---------------------------------------------------------------------------
__global__ __launch_bounds__(256) void q_stage1(const float* __restrict__ errT,
                                                const float* __restrict__ OmT,
                                                const float* __restrict__ Pn,
                                                float* __restrict__ scr) {
  int ec = blockIdx.x, tb = blockIdx.y, b = blockIdx.z;
  int t = tb * 256 + threadIdx.x;
  float Ms[NTRI], rhs[R_];
#pragma unroll
  for (int i = 0; i < NTRI; i++) Ms[i] = 0.f;
#pragma unroll
  for (int i = 0; i < R_; i++) rhs[i] = 0.f;
  long base = ((long)b * T_ + t) * E_;
  for (int e = ec * 128; e < ec * 128 + 128; ++e) {
    const float* pr = Pn + ((long)b * E_ + e) * R_;
    float p[R_];
#pragma unroll
    for (int r = 0; r < R_; r++) p[r] = pr[r];
    float w = OmT[base + e];
    float ev = errT[base + e];
    float wp[R_];
#pragma unroll
    for (int r = 0; r < R_; r++) {
      wp[r] = w * p[r];
      rhs[r] = fmaf(ev, p[r], rhs[r]);
    }
    int idx = 0;
#pragma unroll
    for (int r = 0; r < R_; r++)
#pragma unroll
      for (int s = 0; s <= r; s++) {
        Ms[idx] = fmaf(wp[r], p[s], Ms[idx]);
        idx++;
      }
  }
  long so = ((long)b * 4 + ec) * 65 * T_ + t;
#pragma unroll
  for (int i = 0; i < NTRI; i++) scr[so + (long)i * T_] = Ms[i];
#pragma unroll
  for (int i = 0; i < R_; i++) scr[so + (long)(NTRI + i) * T_] = rhs[i];
}

__global__ __launch_bounds__(256) void q_stage2(
    const float* __restrict__ scr, const float* __restrict__ Qin,
    float* __restrict__ Qout, const float* __restrict__ lam_log,
    const float* __restrict__ sk, int step) {
  int idx = blockIdx.x * 256 + threadIdx.x;  // b*T + t
  int b = idx >> 11, t = idx & 2047;
  float Ms[NTRI], rhs[R_], x[R_];
#pragma unroll
  for (int i = 0; i < NTRI; i++) Ms[i] = 0.f;
#pragma unroll
  for (int i = 0; i < R_; i++) rhs[i] = 0.f;
  for (int ec = 0; ec < 4; ++ec) {
    long so = ((long)b * 4 + ec) * 65 * T_ + t;
#pragma unroll
    for (int i = 0; i < NTRI; i++) Ms[i] += scr[so + (long)i * T_];
#pragma unroll
    for (int i = 0; i < R_; i++) rhs[i] += scr[so + (long)(NTRI + i) * T_];
  }
  float lam = expf(lam_log[step]);
  solve10(Ms, rhs, lam, x);
  float s1 = sigmoidf_(sk[step * 3 + 1]);
#pragma unroll
  for (int r = 0; r < R_; r++) {
    float qold = Qin[(long)idx * R_ + r];
    Qout[(long)idx * R_ + r] = qold + s1 * (x[r] - qold);
  }
}

// ---------------------------------------------------------------------------
// datafit: errOut[t][e] = errIn[t][e] - OmT[t][e] * dot(P[e], Q[t])
// ---------------------------------------------------------------------------
__global__ __launch_bounds__(256) void datafit_k(
    const float* __restrict__ errIn, float* __restrict__ errOut,
    const float* __restrict__ OmT, const float* __restrict__ Pn,
    const float* __restrict__ Qn) {
  int tc = blockIdx.x, eb = blockIdx.y, b = blockIdx.z;
  int e = eb * 256 + threadIdx.x;
  float p[R_];
#pragma unroll
  for (int r = 0; r < R_; r++) p[r] = Pn[((long)b * E_ + e) * R_ + r];
  for (int t = tc * 16; t < tc * 16 + 16; ++t) {
    const float* qr = Qn + ((long)b * T_ + t) * R_;
    float dot = 0.f;
#pragma unroll
    for (int r = 0; r < R_; r++) dot = fmaf(p[r], qr[r], dot);
    long ix = ((long)b * T_ + t) * E_ + e;
    errOut[ix] = errIn[ix] - OmT[ix] * dot;
  }
}

// ---------------------------------------------------------------------------
extern "C" void kernel_launch(void* const* d_in, const int* in_sizes, int n_in,
                              void* d_out, int out_size, void* d_ws,
                              size_t ws_size, hipStream_t stream) {
  const float* Y = (const float*)d_in[0];
  const float* Rm = (const float*)d_in[1];
  const float* Om = (const float*)d_in[2];
  const float* P0 = (const float*)d_in[3];
  const float* Q0 = (const float*)d_in[4];
  const float* lam_log = (const float*)d_in[6];
  const float* mu_log = (const float*)d_in[7];
  const float* sk = (const float*)d_in[8];

  float* ws = (float*)d_ws;
  float* OmT = ws;                       // B*T*E
  float* YOm = OmT + (long)B_ * T_ * E_; // B*T*E
  float* errT = YOm + (long)B_ * T_ * E_;
  float* AscT = errT + (long)B_ * T_ * E_;  // B*T*F
  float* Rt = AscT + (long)B_ * T_ * F_;    // B*F*E
  float* Pa = Rt + (long)B_ * F_ * E_;
  float* Pb = Pa + B_ * E_ * R_;
  float* Qa = Pb + B_ * E_ * R_;
  float* Qb = Qa + B_ * T_ * R_;
  float* scr = Qb + B_ * T_ * R_;  // 4,259,840 floats

  float* outP = (float*)d_out;
  float* outQ = outP + B_ * E_ * R_;
  float* AT = outQ + B_ * T_ * R_;  // A^T [T,F] lives in the out-A region

  const float* Pr[L_] = {P0, Pa, Pb, Pa, Pb};
  float* Pw[L_] = {Pa, Pb, Pa, Pb, outP};
  const float* Qr[L_] = {Q0, Qa, Qb, Qa, Qb};
  float* Qw[L_] = {Qa, Qb, Qa, Qb, outQ};

  dim3 blk(256);
  // ---- prepass (loop-invariant) ----
  trans_k<0><<<dim3(T_ / 32, E_ / 32, B_), blk, 0, stream>>>(Om, nullptr, OmT,
                                                             E_, T_);
  trans_k<1><<<dim3(T_ / 32, E_ / 32, B_), blk, 0, stream>>>(Y, Om, YOm, E_,
                                                             T_);
  trans_k<0><<<dim3(F_ / 32, E_ / 32, B_), blk, 0, stream>>>(Rm, nullptr, Rt,
                                                             E_, F_);
  // Ascale^T[T,F] = OmT @ (Rt^2)^T
  gemm_split<EPI_STORE, 1><<<dim3(F_ / BN_, T_ / BM_, B_), blk, 0, stream>>>(
      OmT, Rt, AscT, nullptr, nullptr, nullptr, nullptr, 0, T_, F_, E_,
      (long)T_ * E_, (long)F_ * E_, (long)T_ * F_);

  for (int s = 0; s < L_; ++s) {
    const float* errS = (s == 0) ? YOm : errT;
    if (s > 0) {
      // errT[T,E] = YOm - OmT * (AT @ R^T)
      gemm_split<EPI_ERR, 0><<<dim3(E_ / BN_, T_ / BM_, B_), blk, 0, stream>>>(
          AT, Rm, errT, YOm, OmT, nullptr, nullptr, s, T_, E_, F_,
          (long)T_ * F_, (long)E_ * F_, (long)T_ * E_);
    }
    p_stage1<<<dim3(16, 2, B_), blk, 0, stream>>>(errS, OmT, Qr[s], scr);
    p_stage2<<<16, blk, 0, stream>>>(scr, Pr[s], Pw[s], lam_log, sk, s);
    q_stage1<<<dim3(4, 8, B_), blk, 0, stream>>>(errS, OmT, Pw[s], scr);
    q_stage2<<<64, blk, 0, stream>>>(scr, Qr[s], Qw[s], lam_log, sk, s);
    datafit_k<<<dim3(128, 2, B_), blk, 0, stream>>>(errS, errT, OmT, Pw[s],
                                                    Qw[s]);
    // AT[T,F] update: C = errT @ Rt^T, fused soft-threshold epilogue
    if (s == 0)
      gemm_split<EPI_AUPD0, 0>
          <<<dim3(F_ / BN_, T_ / BM_, B_), blk, 0, stream>>>(
              errT, Rt, AT, AscT, nullptr, mu_log, sk, s, T_, F_, E_,
              (long)T_ * E_, (long)F_ * E_, (long)T_ * F_);
    else
      gemm_split<EPI_AUPD, 0><<<dim3(F_ / BN_, T_ / BM_, B_), blk, 0, stream>>>(
          errT, Rt, AT, AscT, nullptr, mu_log, sk, s, T_, F_, E_,
          (long)T_ * E_, (long)F_ * E_, (long)T_ * F_);
  }
  // ---- final: AT [T,F] -> A [F,T] per batch (bounce through scr) ----
  for (int b = 0; b < B_; ++b) {
    trans_k<0><<<dim3(F_ / 32, T_ / 32, 1), blk, 0, stream>>>(
        AT + (long)b * T_ * F_, nullptr, scr, T_, F_);
    hipMemcpyAsync(AT + (long)b * T_ * F_, scr, (long)T_ * F_ * sizeof(float),
                   hipMemcpyDeviceToDevice, stream);
  }
}